// Round 7
// baseline (999.708 us; speedup 1.0000x reference)
//
#include <hip/hip_runtime.h>
#include <math.h>

#define B_SZ   4
#define T_SEQ  2048
#define EMB    1024
#define HEADS  16
#define HS     64
#define M_TOT  (B_SZ * T_SEQ)   // 8192

typedef unsigned short u16;
using f32x4  = __attribute__((ext_vector_type(4))) float;
using bf16x8 = __attribute__((ext_vector_type(8))) short;
using u16x8  = __attribute__((ext_vector_type(8))) unsigned short;
using u16x4  = __attribute__((ext_vector_type(4))) unsigned short;

// async global->LDS, 16B per lane; LDS dest is wave-uniform base, HW adds lane*16
__device__ __forceinline__ void async16(u16* lds, const u16* g) {
    __builtin_amdgcn_global_load_lds(
        (const __attribute__((address_space(1))) unsigned int*)g,
        (__attribute__((address_space(3))) unsigned int*)lds, 16, 0, 0);
}

__device__ __forceinline__ u16 bf16_rne(float f) {
    unsigned u = __float_as_uint(f);
    return (u16)((u + 0x7fffu + ((u >> 16) & 1u)) >> 16);
}
__device__ __forceinline__ void split2(float f, u16& h, u16& l) {
    h = bf16_rne(f);
    float hf = __uint_as_float(((unsigned)h) << 16);
    l = bf16_rne(f - hf);
}
__device__ __forceinline__ unsigned cvt_pk_bf16(float a, float b) {
    unsigned r;
    asm("v_cvt_pk_bf16_f32 %0, %1, %2" : "=v"(r) : "v"(a), "v"(b));
    return r;
}

// ---------------------------------------------------------------------------
// One merged split pass: x (8 regions) + Wq/Wk/Wv/Wo (1 region each).
// ---------------------------------------------------------------------------
__global__ __launch_bounds__(256) void split_all(
    const float* __restrict__ x,  const float* __restrict__ wq,
    const float* __restrict__ wk, const float* __restrict__ wv,
    const float* __restrict__ wo,
    u16* __restrict__ xh,  u16* __restrict__ xl,
    u16* __restrict__ wqh, u16* __restrict__ wql,
    u16* __restrict__ wkh, u16* __restrict__ wkl,
    u16* __restrict__ wvh, u16* __restrict__ wvl,
    u16* __restrict__ woh, u16* __restrict__ wol)
{
    int i = blockIdx.x * 256 + threadIdx.x;
    int r = i >> 18;
    const float* src; u16* dh; u16* dl; int off;
    if (r < 8)       { src = x;  dh = xh;  dl = xl;  off = i; }
    else if (r == 8) { src = wq; dh = wqh; dl = wql; off = i - (8 << 18); }
    else if (r == 9) { src = wk; dh = wkh; dl = wkl; off = i - (9 << 18); }
    else if (r == 10){ src = wv; dh = wvh; dl = wvl; off = i - (10 << 18); }
    else             { src = wo; dh = woh; dl = wol; off = i - (11 << 18); }
    float4 v = ((const float4*)src)[off];
    float f[4] = {v.x, v.y, v.z, v.w};
    u16 hh[4], ll[4];
    #pragma unroll
    for (int j = 0; j < 4; ++j) split2(f[j], hh[j], ll[j]);
    uint2 H, L;
    H.x = (unsigned)hh[0] | ((unsigned)hh[1] << 16);
    H.y = (unsigned)hh[2] | ((unsigned)hh[3] << 16);
    L.x = (unsigned)ll[0] | ((unsigned)ll[1] << 16);
    L.y = (unsigned)ll[2] | ((unsigned)ll[3] << 16);
    ((uint2*)dh)[off] = H;
    ((uint2*)dl)[off] = L;
}

// ---------------------------------------------------------------------------
// Split-bf16 MFMA GEMM (known-good, unchanged).
// mode 0: fp32 out + bias; mode 1: per-head LN -> hi/lo bf16;
// mode 2: hi/lo bf16 transposed Vt[b][h][d][t].
// ---------------------------------------------------------------------------
#define BM 128
#define BN 128
#define BKB 32

__global__ __launch_bounds__(256, 2) void gemm_mfma(
    const u16* __restrict__ Ah, const u16* __restrict__ Al,
    const u16* __restrict__ Wh, const u16* __restrict__ Wl,
    float* __restrict__ Cf, u16* __restrict__ Chi, u16* __restrict__ Clo,
    const float* __restrict__ lng, const float* __restrict__ lnb,
    float post_scale, const float* __restrict__ bias, int mode)
{
    __shared__ u16 sAh[BM * BKB], sAl[BM * BKB];
    __shared__ u16 sBh[BN * BKB], sBl[BN * BKB];
    const int tid = threadIdx.x;
    const int w = tid >> 6, lane = tid & 63;
    const int wr = w >> 1, wc = w & 1;
    const int m0 = blockIdx.x * BM, n0 = blockIdx.y * BN;
    const int fr = lane & 15, kc = (lane >> 4) * 8;
    const int srow = lane >> 2, schunk = (lane & 3) * 8;

    f32x4 acc[4][4] = {};

    for (int k0 = 0; k0 < EMB; k0 += BKB) {
        #pragma unroll
        for (int c = 0; c < 2; ++c) {
            int r = (w * 2 + c) * 16 + srow;
            size_t gA = (size_t)(m0 + r) * EMB + k0 + schunk;
            size_t gB = (size_t)(n0 + r) * EMB + k0 + schunk;
            int lb = (w * 2 + c) * 512;
            async16(&sAh[lb], Ah + gA);
            async16(&sAl[lb], Al + gA);
            async16(&sBh[lb], Wh + gB);
            async16(&sBl[lb], Wl + gB);
        }
        __syncthreads();

        bf16x8 bh[4], bl[4];
        #pragma unroll
        for (int ni = 0; ni < 4; ++ni) {
            int row = wc * 64 + ni * 16 + fr;
            bh[ni] = *(const bf16x8*)&sBh[row * BKB + kc];
            bl[ni] = *(const bf16x8*)&sBl[row * BKB + kc];
        }
        #pragma unroll
        for (int mi = 0; mi < 4; ++mi) {
            int row = wr * 64 + mi * 16 + fr;
            bf16x8 ah = *(const bf16x8*)&sAh[row * BKB + kc];
            bf16x8 al = *(const bf16x8*)&sAl[row * BKB + kc];
            #pragma unroll
            for (int ni = 0; ni < 4; ++ni) {
                acc[mi][ni] = __builtin_amdgcn_mfma_f32_16x16x32_bf16(ah, bh[ni], acc[mi][ni], 0, 0, 0);
                acc[mi][ni] = __builtin_amdgcn_mfma_f32_16x16x32_bf16(ah, bl[ni], acc[mi][ni], 0, 0, 0);
                acc[mi][ni] = __builtin_amdgcn_mfma_f32_16x16x32_bf16(al, bh[ni], acc[mi][ni], 0, 0, 0);
            }
        }
        __syncthreads();
    }

    if (mode == 1) {
        float g4[4], b4[4];
        #pragma unroll
        for (int ni = 0; ni < 4; ++ni) {
            int dd = ni * 16 + fr;
            g4[ni] = lng[dd];
            b4[ni] = lnb[dd];
        }
        #pragma unroll
        for (int mi = 0; mi < 4; ++mi) {
            #pragma unroll
            for (int i = 0; i < 4; ++i) {
                float s = acc[mi][0][i] + acc[mi][1][i] + acc[mi][2][i] + acc[mi][3][i];
                #pragma unroll
                for (int off = 1; off < 16; off <<= 1) s += __shfl_xor(s, off);
                float mu = s * (1.f / HS);
                float d2 = 0.f;
                #pragma unroll
                for (int ni = 0; ni < 4; ++ni) {
                    float d = acc[mi][ni][i] - mu;
                    d2 += d * d;
                }
                #pragma unroll
                for (int off = 1; off < 16; off <<= 1) d2 += __shfl_xor(d2, off);
                float rs = rsqrtf(d2 * (1.f / HS) + 1e-5f);
                #pragma unroll
                for (int ni = 0; ni < 4; ++ni)
                    acc[mi][ni][i] = ((acc[mi][ni][i] - mu) * rs * g4[ni] + b4[ni]) * post_scale;
            }
        }
    }

    #pragma unroll
    for (int mi = 0; mi < 4; ++mi) {
        #pragma unroll
        for (int ni = 0; ni < 4; ++ni) {
            const int col = n0 + wc * 64 + ni * 16 + fr;
            const int rowb = m0 + wr * 64 + mi * 16 + (lane >> 4) * 4;
            if (mode == 0) {
                float badd = bias[col];
                #pragma unroll
                for (int i = 0; i < 4; ++i)
                    Cf[(size_t)(rowb + i) * EMB + col] = acc[mi][ni][i] + badd;
            } else if (mode == 1) {
                #pragma unroll
                for (int i = 0; i < 4; ++i) {
                    u16 hh, ll; split2(acc[mi][ni][i], hh, ll);
                    Chi[(size_t)(rowb + i) * EMB + col] = hh;
                    Clo[(size_t)(rowb + i) * EMB + col] = ll;
                }
            } else {
                int hh = col >> 6, d = col & 63;
                int bb = rowb >> 11, t0 = rowb & 2047;
                u16x4 H, L;
                #pragma unroll
                for (int i = 0; i < 4; ++i) {
                    u16 vh, vl; split2(acc[mi][ni][i], vh, vl);
                    H[i] = vh; L[i] = vl;
                }
                size_t off = ((size_t)((bb * HEADS + hh) * HS + d)) * T_SEQ + t0;
                *(u16x4*)(Chi + off) = H;
                *(u16x4*)(Clo + off) = L;
            }
        }
    }
}

// ---------------------------------------------------------------------------
// MFMA flash attention v3 = round-3 per-wave code, 8 waves (256 q-rows/block).
// Each wave stages HALF of one K/V buffer (wave -> buffer w>>1, half w&1).
// LDS ~76 KB -> 2 blocks/CU x 8 waves = 16 waves/CU (2x round-3 occupancy).
// ---------------------------------------------------------------------------
__global__ __launch_bounds__(512, 4) void attn_mfma(
    const u16* __restrict__ qh, const u16* __restrict__ ql,
    const u16* __restrict__ kh, const u16* __restrict__ kl,
    const u16* __restrict__ vh, const u16* __restrict__ vl,
    const int* __restrict__ mask,
    u16* __restrict__ oh, u16* __restrict__ ol)
{
    __shared__ u16 sKh[64 * 72], sKl[64 * 72], sVh[64 * 72], sVl[64 * 72];
    __shared__ u16 sPs[8][32 * 72];
    __shared__ float kmsh[64];
    __shared__ float qmsh[256];
    __shared__ float fb[8][32];

    const int tid = threadIdx.x;
    const int w = tid >> 6, lane = tid & 63;
    const int fr = lane & 15, g = lane >> 4;
    const int q0 = blockIdx.x * 256;
    const int h = blockIdx.y, b = blockIdx.z;

    if (tid < 256) qmsh[tid] = (float)mask[b * T_SEQ + q0 + tid];

    // staging: wave w -> buffer (w>>1), half (w&1); 32 rows x 64 u16 per wave
    const int bsel = w >> 1, half = w & 1;
    const u16* gsrc; u16* sdst; int rstr; size_t kstep;
    if (bsel == 0)      { gsrc = kh + (size_t)b * T_SEQ * EMB + h * HS; sdst = sKh; rstr = EMB;   kstep = (size_t)64 * EMB; }
    else if (bsel == 1) { gsrc = kl + (size_t)b * T_SEQ * EMB + h * HS; sdst = sKl; rstr = EMB;   kstep = (size_t)64 * EMB; }
    else if (bsel == 2) { gsrc = vh + (size_t)(b * HEADS + h) * HS * T_SEQ; sdst = sVh; rstr = T_SEQ; kstep = 64; }
    else                { gsrc = vl + (size_t)(b * HEADS + h) * HS * T_SEQ; sdst = sVl; rstr = T_SEQ; kstep = 64; }
    gsrc += (size_t)half * 32 * rstr;
    sdst += half * 32 * 72;

    // Q fragments in registers (B-operand of swapped QK^T); wave owns 32 q-rows
    bf16x8 qfh[2][2], qfl[2][2];
    #pragma unroll
    for (int nf = 0; nf < 2; ++nf)
        #pragma unroll
        for (int ks = 0; ks < 2; ++ks) {
            size_t off = (size_t)(b * T_SEQ + q0 + w * 32 + nf * 16 + fr) * EMB
                         + h * HS + g * 8 + ks * 32;
            qfh[nf][ks] = *(const bf16x8*)(qh + off);
            qfl[nf][ks] = *(const bf16x8*)(ql + off);
        }

    f32x4 o[2][4] = {};
    float mrun[2] = {-INFINITY, -INFINITY}, lrun[2] = {0.f, 0.f};
    u16* Psw = sPs[w];

    for (int kt = 0; kt < T_SEQ / 64; ++kt) {
        // ---- stage K/V half-tile (each wave: 32 rows of one buffer) ----
        const u16* src = gsrc + (size_t)kt * kstep;
        u16x8 stg[4];
        #pragma unroll
        for (int it = 0; it < 4; ++it) {
            int idx = it * 64 + lane;
            stg[it] = *(const u16x8*)(src + (size_t)(idx >> 3) * rstr + (idx & 7) * 8);
        }
        #pragma unroll
        for (int it = 0; it < 4; ++it) {
            int idx = it * 64 + lane;
            *(u16x8*)&sdst[(idx >> 3) * 72 + (idx & 7) * 8] = stg[it];
        }
        if (tid < 64) kmsh[tid] = (float)mask[b * T_SEQ + kt * 64 + tid];
        __syncthreads();

        float kmv[4][4]; int anyv = 0;
        #pragma unroll
        for (int mf = 0; mf < 4; ++mf)
            #pragma unroll
            for (int i = 0; i < 4; ++i) {
                kmv[mf][i] = kmsh[mf * 16 + g * 4 + i];
                anyv |= (kmv[mf][i] != 0.f);
            }

        if (__any(anyv)) {
            // ---- QK^T (swapped): st[key][q] ----
            f32x4 st[4][2] = {};
            #pragma unroll
            for (int ks = 0; ks < 2; ++ks) {
                bf16x8 ka[4], kb[4];
                #pragma unroll
                for (int mf = 0; mf < 4; ++mf) {
                    ka[mf] = *(const bf16x8*)&sKh[(mf * 16 + fr) * 72 + g * 8 + ks * 32];
                    kb[mf] = *(const bf16x8*)&sKl[(mf * 16 + fr) * 72 + g * 8 + ks * 32];
                }
                __builtin_amdgcn_s_setprio(1);
                #pragma unroll
                for (int mf = 0; mf < 4; ++mf)
                    #pragma unroll
                    for (int nf = 0; nf < 2; ++nf) {
                        st[mf][nf] = __builtin_amdgcn_mfma_f32_16x16x32_bf16(ka[mf], qfh[nf][ks], st[mf][nf], 0, 0, 0);
                        st[mf][nf] = __builtin_amdgcn_mfma_f32_16x16x32_bf16(ka[mf], qfl[nf][ks], st[mf][nf], 0, 0, 0);
                        st[mf][nf] = __builtin_amdgcn_mfma_f32_16x16x32_bf16(kb[mf], qfh[nf][ks], st[mf][nf], 0, 0, 0);
                    }
                __builtin_amdgcn_s_setprio(0);
            }
            // ---- online softmax (per q = lane&15 + 16*nf) ----
            #pragma unroll
            for (int nf = 0; nf < 2; ++nf) {
                float tm = -INFINITY;
                #pragma unroll
                for (int mf = 0; mf < 4; ++mf)
                    #pragma unroll
                    for (int i = 0; i < 4; ++i) {
                        float s = (kmv[mf][i] != 0.f) ? st[mf][nf][i] : -INFINITY;
                        st[mf][nf][i] = s;
                        tm = fmaxf(tm, s);
                    }
                tm = fmaxf(tm, __shfl_xor(tm, 16));
                tm = fmaxf(tm, __shfl_xor(tm, 32));
                float mn = fmaxf(mrun[nf], tm);
                if (mn != -INFINITY) {
                    float f = __expf(mrun[nf] - mn);
                    float ps = 0.f;
                    #pragma unroll
                    for (int mf = 0; mf < 4; ++mf)
                        #pragma unroll
                        for (int i = 0; i < 4; ++i) {
                            float p = __expf(st[mf][nf][i] - mn);
                            st[mf][nf][i] = p;
                            ps += p;
                        }
                    ps += __shfl_xor(ps, 16);
                    ps += __shfl_xor(ps, 32);
                    lrun[nf] = lrun[nf] * f + ps;
                    mrun[nf] = mn;
                    fb[w][nf * 16 + fr] = f;
                } else {
                    #pragma unroll
                    for (int mf = 0; mf < 4; ++mf)
                        #pragma unroll
                        for (int i = 0; i < 4; ++i) st[mf][nf][i] = 0.f;
                    fb[w][nf * 16 + fr] = 1.f;
                }
            }
            // ---- P -> bf16 -> LDS (A-operand layout for PV) ----
            #pragma unroll
            for (int nf = 0; nf < 2; ++nf)
                #pragma unroll
                for (int mf = 0; mf < 4; ++mf)
                    #pragma unroll
                    for (int i = 0; i < 4; i += 2) {
                        unsigned pk = cvt_pk_bf16(st[mf][nf][i], st[mf][nf][i + 1]);
                        *(unsigned*)&Psw[(nf * 16 + fr) * 72 + mf * 16 + g * 4 + i] = pk;
                    }
            // ---- rescale O by f (O-layout q = mi*16 + g*4 + i) ----
            float ff[2][4];
            #pragma unroll
            for (int mi = 0; mi < 2; ++mi)
                #pragma unroll
                for (int i = 0; i < 4; ++i)
                    ff[mi][i] = fb[w][mi * 16 + g * 4 + i];
            #pragma unroll
            for (int mi = 0; mi < 2; ++mi)
                #pragma unroll
                for (int nj = 0; nj < 4; ++nj)
                    #pragma unroll
                    for (int i = 0; i < 4; ++i)
                        o[mi][nj][i] *= ff[mi][i];
            // ---- PV ----
            #pragma unroll
            for (int ks = 0; ks < 2; ++ks) {
                bf16x8 pa[2];
                #pragma unroll
                for (int mi = 0; mi < 2; ++mi)
                    pa[mi] = *(const bf16x8*)&Psw[(mi * 16 + fr) * 72 + g * 8 + ks * 32];
                __builtin_amdgcn_s_setprio(1);
                #pragma unroll
                for (int nj = 0; nj < 4; ++nj) {
                    bf16x8 va = *(const bf16x8*)&sVh[(nj * 16 + fr) * 72 + g * 8 + ks * 32];
                    bf16x8 vb = *(const bf16x8*)&sVl[(nj * 16 + fr) * 72 + g * 8 + ks * 32];
                    #pragma unroll
                    for (int mi = 0; mi < 2; ++mi) {
                        o[mi][nj] = __builtin_amdgcn_mfma_f32_16x16x32_bf16(pa[mi], va, o[mi][nj], 0, 0, 0);
                        o[mi][nj] = __builtin_amdgcn_mfma_f32_16x16x32_bf16(pa[mi], vb, o[mi][nj], 0, 0, 0);
                    }
                }
                __builtin_amdgcn_s_setprio(0);
            }
        }
        __syncthreads();
    }

    // ---- epilogue: normalize, mask q, write hi/lo bf16 ----
    #pragma unroll
    for (int nf = 0; nf < 2; ++nf) fb[w][nf * 16 + fr] = lrun[nf];
    #pragma unroll
    for (int mi = 0; mi < 2; ++mi) {
        #pragma unroll
        for (int i = 0; i < 4; ++i) {
            float lq = fb[w][mi * 16 + g * 4 + i];
            float qv = qmsh[w * 32 + mi * 16 + g * 4 + i];
            float inv = (qv != 0.f && lq > 0.f) ? 1.f / lq : 0.f;
            size_t row = (size_t)(b * T_SEQ + q0 + w * 32 + mi * 16 + g * 4 + i);
            #pragma unroll
            for (int nj = 0; nj < 4; ++nj) {
                float v = o[mi][nj][i] * inv;
                u16 hh, ll; split2(v, hh, ll);
                size_t off = row * EMB + h * HS + nj * 16 + fr;
                oh[off] = hh;
                ol[off] = ll;
            }
        }
    }
}

// ---------------------------------------------------------------------------
extern "C" void kernel_launch(void* const* d_in, const int* in_sizes, int n_in,
                              void* d_out, int out_size, void* d_ws, size_t ws_size,
                              hipStream_t stream)
{
    const float* x    = (const float*)d_in[0];
    const int*   mask = (const int*)d_in[1];
    const float* Wk   = (const float*)d_in[2];
    const float* Wq   = (const float*)d_in[3];
    const float* Wv   = (const float*)d_in[4];
    const float* Wo   = (const float*)d_in[5];
    const float* bo   = (const float*)d_in[6];
    const float* kg   = (const float*)d_in[7];
    const float* kbb  = (const float*)d_in[8];
    const float* qg   = (const float*)d_in[9];
    const float* qbb  = (const float*)d_in[10];
    float* out = (float*)d_out;

    const size_t NELT = (size_t)M_TOT * EMB;   // 8,388,608
    const size_t WELT = (size_t)EMB * EMB;     // 1,048,576
    u16* xh  = (u16*)d_ws;            // also reused as attn output hi
    u16* xl  = xh + NELT;             // also reused as attn output lo
    u16* p_qh = xl + NELT;
    u16* p_ql = p_qh + NELT;
    u16* p_kh = p_ql + NELT;
    u16* p_kl = p_kh + NELT;
    u16* p_vh = p_kl + NELT;          // transposed [b][h][d][t]
    u16* p_vl = p_vh + NELT;
    u16* wqh = p_vl + NELT;
    u16* wql = wqh + WELT;
    u16* wkh = wql + WELT;
    u16* wkl = wkh + WELT;
    u16* wvh = wkl + WELT;
    u16* wvl = wvh + WELT;
    u16* woh = wvl + WELT;
    u16* wol = woh + WELT;

    const float ps = 0.17677669529663687f;     // 1024^(-1/4)

    split_all<<<12288, 256, 0, stream>>>(x, Wq, Wk, Wv, Wo,
        xh, xl, wqh, wql, wkh, wkl, wvh, wvl, woh, wol);

    dim3 ggrid(M_TOT / BM, EMB / BN);
    gemm_mfma<<<ggrid, 256, 0, stream>>>(xh, xl, wqh, wql, nullptr, p_qh, p_ql, qg, qbb, ps, nullptr, 1);
    gemm_mfma<<<ggrid, 256, 0, stream>>>(xh, xl, wkh, wkl, nullptr, p_kh, p_kl, kg, kbb, ps, nullptr, 1);
    gemm_mfma<<<ggrid, 256, 0, stream>>>(xh, xl, wvh, wvl, nullptr, p_vh, p_vl, nullptr, nullptr, 1.f, nullptr, 2);

    dim3 agrid(T_SEQ / 256, HEADS, B_SZ);
    attn_mfma<<<agrid, 512, 0, stream>>>(p_qh, p_ql, p_kh, p_kl, p_vh, p_vl, mask, xh, xl);

    gemm_mfma<<<ggrid, 256, 0, stream>>>(xh, xl, woh, wol, out, nullptr, nullptr, nullptr, nullptr, 1.f, bo, 0);
}

// Round 8
// 568.103 us; speedup vs baseline: 1.7597x; 1.7597x over previous
//
#include <hip/hip_runtime.h>
#include <math.h>

#define B_SZ   4
#define T_SEQ  2048
#define EMB    1024
#define HEADS  16
#define HS     64
#define M_TOT  (B_SZ * T_SEQ)   // 8192

typedef unsigned short u16;
using f32x4  = __attribute__((ext_vector_type(4))) float;
using bf16x8 = __attribute__((ext_vector_type(8))) short;
using u16x8  = __attribute__((ext_vector_type(8))) unsigned short;
using u16x4  = __attribute__((ext_vector_type(4))) unsigned short;

// async global->LDS, 16B per lane; LDS dest is wave-uniform base, HW adds lane*16
__device__ __forceinline__ void async16(u16* lds, const u16* g) {
    __builtin_amdgcn_global_load_lds(
        (const __attribute__((address_space(1))) unsigned int*)g,
        (__attribute__((address_space(3))) unsigned int*)lds, 16, 0, 0);
}

__device__ __forceinline__ u16 bf16_rne(float f) {
    unsigned u = __float_as_uint(f);
    return (u16)((u + 0x7fffu + ((u >> 16) & 1u)) >> 16);
}
__device__ __forceinline__ void split2(float f, u16& h, u16& l) {
    h = bf16_rne(f);
    float hf = __uint_as_float(((unsigned)h) << 16);
    l = bf16_rne(f - hf);
}
__device__ __forceinline__ unsigned cvt_pk_bf16(float a, float b) {
    unsigned r;
    asm("v_cvt_pk_bf16_f32 %0, %1, %2" : "=v"(r) : "v"(a), "v"(b));
    return r;
}

// ---------------------------------------------------------------------------
// One merged split pass: x (8 regions) + Wq/Wk/Wv/Wo (1 region each).
// ---------------------------------------------------------------------------
__global__ __launch_bounds__(256) void split_all(
    const float* __restrict__ x,  const float* __restrict__ wq,
    const float* __restrict__ wk, const float* __restrict__ wv,
    const float* __restrict__ wo,
    u16* __restrict__ xh,  u16* __restrict__ xl,
    u16* __restrict__ wqh, u16* __restrict__ wql,
    u16* __restrict__ wkh, u16* __restrict__ wkl,
    u16* __restrict__ wvh, u16* __restrict__ wvl,
    u16* __restrict__ woh, u16* __restrict__ wol)
{
    int i = blockIdx.x * 256 + threadIdx.x;
    int r = i >> 18;
    const float* src; u16* dh; u16* dl; int off;
    if (r < 8)       { src = x;  dh = xh;  dl = xl;  off = i; }
    else if (r == 8) { src = wq; dh = wqh; dl = wql; off = i - (8 << 18); }
    else if (r == 9) { src = wk; dh = wkh; dl = wkl; off = i - (9 << 18); }
    else if (r == 10){ src = wv; dh = wvh; dl = wvl; off = i - (10 << 18); }
    else             { src = wo; dh = woh; dl = wol; off = i - (11 << 18); }
    float4 v = ((const float4*)src)[off];
    float f[4] = {v.x, v.y, v.z, v.w};
    u16 hh[4], ll[4];
    #pragma unroll
    for (int j = 0; j < 4; ++j) split2(f[j], hh[j], ll[j]);
    uint2 H, L;
    H.x = (unsigned)hh[0] | ((unsigned)hh[1] << 16);
    H.y = (unsigned)hh[2] | ((unsigned)hh[3] << 16);
    L.x = (unsigned)ll[0] | ((unsigned)ll[1] << 16);
    L.y = (unsigned)ll[2] | ((unsigned)ll[3] << 16);
    ((uint2*)dh)[off] = H;
    ((uint2*)dl)[off] = L;
}

// ---------------------------------------------------------------------------
// Split-bf16 MFMA GEMM (known-good, unchanged).
// mode 0: fp32 out + bias; mode 1: per-head LN -> hi/lo bf16;
// mode 2: hi/lo bf16 transposed Vt[b][h][d][t].
// ---------------------------------------------------------------------------
#define BM 128
#define BN 128
#define BKB 32

__global__ __launch_bounds__(256, 2) void gemm_mfma(
    const u16* __restrict__ Ah, const u16* __restrict__ Al,
    const u16* __restrict__ Wh, const u16* __restrict__ Wl,
    float* __restrict__ Cf, u16* __restrict__ Chi, u16* __restrict__ Clo,
    const float* __restrict__ lng, const float* __restrict__ lnb,
    float post_scale, const float* __restrict__ bias, int mode)
{
    __shared__ u16 sAh[BM * BKB], sAl[BM * BKB];
    __shared__ u16 sBh[BN * BKB], sBl[BN * BKB];
    const int tid = threadIdx.x;
    const int w = tid >> 6, lane = tid & 63;
    const int wr = w >> 1, wc = w & 1;
    const int m0 = blockIdx.x * BM, n0 = blockIdx.y * BN;
    const int fr = lane & 15, kc = (lane >> 4) * 8;
    const int srow = lane >> 2, schunk = (lane & 3) * 8;

    f32x4 acc[4][4] = {};

    for (int k0 = 0; k0 < EMB; k0 += BKB) {
        #pragma unroll
        for (int c = 0; c < 2; ++c) {
            int r = (w * 2 + c) * 16 + srow;
            size_t gA = (size_t)(m0 + r) * EMB + k0 + schunk;
            size_t gB = (size_t)(n0 + r) * EMB + k0 + schunk;
            int lb = (w * 2 + c) * 512;
            async16(&sAh[lb], Ah + gA);
            async16(&sAl[lb], Al + gA);
            async16(&sBh[lb], Wh + gB);
            async16(&sBl[lb], Wl + gB);
        }
        __syncthreads();

        bf16x8 bh[4], bl[4];
        #pragma unroll
        for (int ni = 0; ni < 4; ++ni) {
            int row = wc * 64 + ni * 16 + fr;
            bh[ni] = *(const bf16x8*)&sBh[row * BKB + kc];
            bl[ni] = *(const bf16x8*)&sBl[row * BKB + kc];
        }
        #pragma unroll
        for (int mi = 0; mi < 4; ++mi) {
            int row = wr * 64 + mi * 16 + fr;
            bf16x8 ah = *(const bf16x8*)&sAh[row * BKB + kc];
            bf16x8 al = *(const bf16x8*)&sAl[row * BKB + kc];
            #pragma unroll
            for (int ni = 0; ni < 4; ++ni) {
                acc[mi][ni] = __builtin_amdgcn_mfma_f32_16x16x32_bf16(ah, bh[ni], acc[mi][ni], 0, 0, 0);
                acc[mi][ni] = __builtin_amdgcn_mfma_f32_16x16x32_bf16(ah, bl[ni], acc[mi][ni], 0, 0, 0);
                acc[mi][ni] = __builtin_amdgcn_mfma_f32_16x16x32_bf16(al, bh[ni], acc[mi][ni], 0, 0, 0);
            }
        }
        __syncthreads();
    }

    if (mode == 1) {
        float g4[4], b4[4];
        #pragma unroll
        for (int ni = 0; ni < 4; ++ni) {
            int dd = ni * 16 + fr;
            g4[ni] = lng[dd];
            b4[ni] = lnb[dd];
        }
        #pragma unroll
        for (int mi = 0; mi < 4; ++mi) {
            #pragma unroll
            for (int i = 0; i < 4; ++i) {
                float s = acc[mi][0][i] + acc[mi][1][i] + acc[mi][2][i] + acc[mi][3][i];
                #pragma unroll
                for (int off = 1; off < 16; off <<= 1) s += __shfl_xor(s, off);
                float mu = s * (1.f / HS);
                float d2 = 0.f;
                #pragma unroll
                for (int ni = 0; ni < 4; ++ni) {
                    float d = acc[mi][ni][i] - mu;
                    d2 += d * d;
                }
                #pragma unroll
                for (int off = 1; off < 16; off <<= 1) d2 += __shfl_xor(d2, off);
                float rs = rsqrtf(d2 * (1.f / HS) + 1e-5f);
                #pragma unroll
                for (int ni = 0; ni < 4; ++ni)
                    acc[mi][ni][i] = ((acc[mi][ni][i] - mu) * rs * g4[ni] + b4[ni]) * post_scale;
            }
        }
    }

    #pragma unroll
    for (int mi = 0; mi < 4; ++mi) {
        #pragma unroll
        for (int ni = 0; ni < 4; ++ni) {
            const int col = n0 + wc * 64 + ni * 16 + fr;
            const int rowb = m0 + wr * 64 + mi * 16 + (lane >> 4) * 4;
            if (mode == 0) {
                float badd = bias[col];
                #pragma unroll
                for (int i = 0; i < 4; ++i)
                    Cf[(size_t)(rowb + i) * EMB + col] = acc[mi][ni][i] + badd;
            } else if (mode == 1) {
                #pragma unroll
                for (int i = 0; i < 4; ++i) {
                    u16 hh, ll; split2(acc[mi][ni][i], hh, ll);
                    Chi[(size_t)(rowb + i) * EMB + col] = hh;
                    Clo[(size_t)(rowb + i) * EMB + col] = ll;
                }
            } else {
                int hh = col >> 6, d = col & 63;
                int bb = rowb >> 11, t0 = rowb & 2047;
                u16x4 H, L;
                #pragma unroll
                for (int i = 0; i < 4; ++i) {
                    u16 vh, vl; split2(acc[mi][ni][i], vh, vl);
                    H[i] = vh; L[i] = vl;
                }
                size_t off = ((size_t)((bb * HEADS + hh) * HS + d)) * T_SEQ + t0;
                *(u16x4*)(Chi + off) = H;
                *(u16x4*)(Clo + off) = L;
            }
        }
    }
}

// ---------------------------------------------------------------------------
// MFMA flash attention v3.1 = v3 with the register-cap fix.
// __launch_bounds__(512, 2): 2nd arg behaves as min BLOCKS/CU (observed r7:
// (512,4) -> VGPR cap 64 -> massive scratch spill, WRITE_SIZE 1.1 GB).
// 2 blocks/CU x 8 waves = 16 waves/CU, VGPR cap 128 (round-3 code needs ~112).
// ---------------------------------------------------------------------------
__global__ __launch_bounds__(512, 2) void attn_mfma(
    const u16* __restrict__ qh, const u16* __restrict__ ql,
    const u16* __restrict__ kh, const u16* __restrict__ kl,
    const u16* __restrict__ vh, const u16* __restrict__ vl,
    const int* __restrict__ mask,
    u16* __restrict__ oh, u16* __restrict__ ol)
{
    __shared__ u16 sKh[64 * 72], sKl[64 * 72], sVh[64 * 72], sVl[64 * 72];
    __shared__ u16 sPs[8][32 * 72];
    __shared__ float kmsh[64];
    __shared__ float qmsh[256];
    __shared__ float fb[8][32];

    const int tid = threadIdx.x;
    const int w = tid >> 6, lane = tid & 63;
    const int fr = lane & 15, g = lane >> 4;
    const int q0 = blockIdx.x * 256;
    const int h = blockIdx.y, b = blockIdx.z;

    if (tid < 256) qmsh[tid] = (float)mask[b * T_SEQ + q0 + tid];

    // staging: wave w -> buffer (w>>1), half (w&1); 32 rows x 64 u16 per wave
    const int bsel = w >> 1, half = w & 1;
    const u16* gsrc; u16* sdst; int rstr; size_t kstep;
    if (bsel == 0)      { gsrc = kh + (size_t)b * T_SEQ * EMB + h * HS; sdst = sKh; rstr = EMB;   kstep = (size_t)64 * EMB; }
    else if (bsel == 1) { gsrc = kl + (size_t)b * T_SEQ * EMB + h * HS; sdst = sKl; rstr = EMB;   kstep = (size_t)64 * EMB; }
    else if (bsel == 2) { gsrc = vh + (size_t)(b * HEADS + h) * HS * T_SEQ; sdst = sVh; rstr = T_SEQ; kstep = 64; }
    else                { gsrc = vl + (size_t)(b * HEADS + h) * HS * T_SEQ; sdst = sVl; rstr = T_SEQ; kstep = 64; }
    gsrc += (size_t)half * 32 * rstr;
    sdst += half * 32 * 72;

    // Q fragments in registers (B-operand of swapped QK^T); wave owns 32 q-rows
    bf16x8 qfh[2][2], qfl[2][2];
    #pragma unroll
    for (int nf = 0; nf < 2; ++nf)
        #pragma unroll
        for (int ks = 0; ks < 2; ++ks) {
            size_t off = (size_t)(b * T_SEQ + q0 + w * 32 + nf * 16 + fr) * EMB
                         + h * HS + g * 8 + ks * 32;
            qfh[nf][ks] = *(const bf16x8*)(qh + off);
            qfl[nf][ks] = *(const bf16x8*)(ql + off);
        }

    f32x4 o[2][4] = {};
    float mrun[2] = {-INFINITY, -INFINITY}, lrun[2] = {0.f, 0.f};
    u16* Psw = sPs[w];

    for (int kt = 0; kt < T_SEQ / 64; ++kt) {
        // ---- stage K/V half-tile (each wave: 32 rows of one buffer) ----
        const u16* src = gsrc + (size_t)kt * kstep;
        u16x8 stg[4];
        #pragma unroll
        for (int it = 0; it < 4; ++it) {
            int idx = it * 64 + lane;
            stg[it] = *(const u16x8*)(src + (size_t)(idx >> 3) * rstr + (idx & 7) * 8);
        }
        #pragma unroll
        for (int it = 0; it < 4; ++it) {
            int idx = it * 64 + lane;
            *(u16x8*)&sdst[(idx >> 3) * 72 + (idx & 7) * 8] = stg[it];
        }
        if (tid < 64) kmsh[tid] = (float)mask[b * T_SEQ + kt * 64 + tid];
        __syncthreads();

        float kmv[4][4]; int anyv = 0;
        #pragma unroll
        for (int mf = 0; mf < 4; ++mf)
            #pragma unroll
            for (int i = 0; i < 4; ++i) {
                kmv[mf][i] = kmsh[mf * 16 + g * 4 + i];
                anyv |= (kmv[mf][i] != 0.f);
            }

        if (__any(anyv)) {
            // ---- QK^T (swapped): st[key][q] ----
            f32x4 st[4][2] = {};
            #pragma unroll
            for (int ks = 0; ks < 2; ++ks) {
                bf16x8 ka[4], kb[4];
                #pragma unroll
                for (int mf = 0; mf < 4; ++mf) {
                    ka[mf] = *(const bf16x8*)&sKh[(mf * 16 + fr) * 72 + g * 8 + ks * 32];
                    kb[mf] = *(const bf16x8*)&sKl[(mf * 16 + fr) * 72 + g * 8 + ks * 32];
                }
                __builtin_amdgcn_s_setprio(1);
                #pragma unroll
                for (int mf = 0; mf < 4; ++mf)
                    #pragma unroll
                    for (int nf = 0; nf < 2; ++nf) {
                        st[mf][nf] = __builtin_amdgcn_mfma_f32_16x16x32_bf16(ka[mf], qfh[nf][ks], st[mf][nf], 0, 0, 0);
                        st[mf][nf] = __builtin_amdgcn_mfma_f32_16x16x32_bf16(ka[mf], qfl[nf][ks], st[mf][nf], 0, 0, 0);
                        st[mf][nf] = __builtin_amdgcn_mfma_f32_16x16x32_bf16(kb[mf], qfh[nf][ks], st[mf][nf], 0, 0, 0);
                    }
                __builtin_amdgcn_s_setprio(0);
            }
            // ---- online softmax (per q = lane&15 + 16*nf) ----
            #pragma unroll
            for (int nf = 0; nf < 2; ++nf) {
                float tm = -INFINITY;
                #pragma unroll
                for (int mf = 0; mf < 4; ++mf)
                    #pragma unroll
                    for (int i = 0; i < 4; ++i) {
                        float s = (kmv[mf][i] != 0.f) ? st[mf][nf][i] : -INFINITY;
                        st[mf][nf][i] = s;
                        tm = fmaxf(tm, s);
                    }
                tm = fmaxf(tm, __shfl_xor(tm, 16));
                tm = fmaxf(tm, __shfl_xor(tm, 32));
                float mn = fmaxf(mrun[nf], tm);
                if (mn != -INFINITY) {
                    float f = __expf(mrun[nf] - mn);
                    float ps = 0.f;
                    #pragma unroll
                    for (int mf = 0; mf < 4; ++mf)
                        #pragma unroll
                        for (int i = 0; i < 4; ++i) {
                            float p = __expf(st[mf][nf][i] - mn);
                            st[mf][nf][i] = p;
                            ps += p;
                        }
                    ps += __shfl_xor(ps, 16);
                    ps += __shfl_xor(ps, 32);
                    lrun[nf] = lrun[nf] * f + ps;
                    mrun[nf] = mn;
                    fb[w][nf * 16 + fr] = f;
                } else {
                    #pragma unroll
                    for (int mf = 0; mf < 4; ++mf)
                        #pragma unroll
                        for (int i = 0; i < 4; ++i) st[mf][nf][i] = 0.f;
                    fb[w][nf * 16 + fr] = 1.f;
                }
            }
            // ---- P -> bf16 -> LDS (A-operand layout for PV) ----
            #pragma unroll
            for (int nf = 0; nf < 2; ++nf)
                #pragma unroll
                for (int mf = 0; mf < 4; ++mf)
                    #pragma unroll
                    for (int i = 0; i < 4; i += 2) {
                        unsigned pk = cvt_pk_bf16(st[mf][nf][i], st[mf][nf][i + 1]);
                        *(unsigned*)&Psw[(nf * 16 + fr) * 72 + mf * 16 + g * 4 + i] = pk;
                    }
            // ---- rescale O by f (O-layout q = mi*16 + g*4 + i) ----
            float ff[2][4];
            #pragma unroll
            for (int mi = 0; mi < 2; ++mi)
                #pragma unroll
                for (int i = 0; i < 4; ++i)
                    ff[mi][i] = fb[w][mi * 16 + g * 4 + i];
            #pragma unroll
            for (int mi = 0; mi < 2; ++mi)
                #pragma unroll
                for (int nj = 0; nj < 4; ++nj)
                    #pragma unroll
                    for (int i = 0; i < 4; ++i)
                        o[mi][nj][i] *= ff[mi][i];
            // ---- PV ----
            #pragma unroll
            for (int ks = 0; ks < 2; ++ks) {
                bf16x8 pa[2];
                #pragma unroll
                for (int mi = 0; mi < 2; ++mi)
                    pa[mi] = *(const bf16x8*)&Psw[(mi * 16 + fr) * 72 + g * 8 + ks * 32];
                __builtin_amdgcn_s_setprio(1);
                #pragma unroll
                for (int nj = 0; nj < 4; ++nj) {
                    bf16x8 va = *(const bf16x8*)&sVh[(nj * 16 + fr) * 72 + g * 8 + ks * 32];
                    bf16x8 vb = *(const bf16x8*)&sVl[(nj * 16 + fr) * 72 + g * 8 + ks * 32];
                    #pragma unroll
                    for (int mi = 0; mi < 2; ++mi) {
                        o[mi][nj] = __builtin_amdgcn_mfma_f32_16x16x32_bf16(pa[mi], va, o[mi][nj], 0, 0, 0);
                        o[mi][nj] = __builtin_amdgcn_mfma_f32_16x16x32_bf16(pa[mi], vb, o[mi][nj], 0, 0, 0);
                    }
                }
                __builtin_amdgcn_s_setprio(0);
            }
        }
        __syncthreads();
    }

    // ---- epilogue: normalize, mask q, write hi/lo bf16 ----
    #pragma unroll
    for (int nf = 0; nf < 2; ++nf) fb[w][nf * 16 + fr] = lrun[nf];
    #pragma unroll
    for (int mi = 0; mi < 2; ++mi) {
        #pragma unroll
        for (int i = 0; i < 4; ++i) {
            float lq = fb[w][mi * 16 + g * 4 + i];
            float qv = qmsh[w * 32 + mi * 16 + g * 4 + i];
            float inv = (qv != 0.f && lq > 0.f) ? 1.f / lq : 0.f;
            size_t row = (size_t)(b * T_SEQ + q0 + w * 32 + mi * 16 + g * 4 + i);
            #pragma unroll
            for (int nj = 0; nj < 4; ++nj) {
                float v = o[mi][nj][i] * inv;
                u16 hh, ll; split2(v, hh, ll);
                size_t off = row * EMB + h * HS + nj * 16 + fr;
                oh[off] = hh;
                ol[off] = ll;
            }
        }
    }
}

// ---------------------------------------------------------------------------
extern "C" void kernel_launch(void* const* d_in, const int* in_sizes, int n_in,
                              void* d_out, int out_size, void* d_ws, size_t ws_size,
                              hipStream_t stream)
{
    const float* x    = (const float*)d_in[0];
    const int*   mask = (const int*)d_in[1];
    const float* Wk   = (const float*)d_in[2];
    const float* Wq   = (const float*)d_in[3];
    const float* Wv   = (const float*)d_in[4];
    const float* Wo   = (const float*)d_in[5];
    const float* bo   = (const float*)d_in[6];
    const float* kg   = (const float*)d_in[7];
    const float* kbb  = (const float*)d_in[8];
    const float* qg   = (const float*)d_in[9];
    const float* qbb  = (const float*)d_in[10];
    float* out = (float*)d_out;

    const size_t NELT = (size_t)M_TOT * EMB;   // 8,388,608
    const size_t WELT = (size_t)EMB * EMB;     // 1,048,576
    u16* xh  = (u16*)d_ws;            // also reused as attn output hi
    u16* xl  = xh + NELT;             // also reused as attn output lo
    u16* p_qh = xl + NELT;
    u16* p_ql = p_qh + NELT;
    u16* p_kh = p_ql + NELT;
    u16* p_kl = p_kh + NELT;
    u16* p_vh = p_kl + NELT;          // transposed [b][h][d][t]
    u16* p_vl = p_vh + NELT;
    u16* wqh = p_vl + NELT;
    u16* wql = wqh + WELT;
    u16* wkh = wql + WELT;
    u16* wkl = wkh + WELT;
    u16* wvh = wkl + WELT;
    u16* wvl = wvh + WELT;
    u16* woh = wvl + WELT;
    u16* wol = woh + WELT;

    const float ps = 0.17677669529663687f;     // 1024^(-1/4)

    split_all<<<12288, 256, 0, stream>>>(x, Wq, Wk, Wv, Wo,
        xh, xl, wqh, wql, wkh, wkl, wvh, wvl, woh, wol);

    dim3 ggrid(M_TOT / BM, EMB / BN);
    gemm_mfma<<<ggrid, 256, 0, stream>>>(xh, xl, wqh, wql, nullptr, p_qh, p_ql, qg, qbb, ps, nullptr, 1);
    gemm_mfma<<<ggrid, 256, 0, stream>>>(xh, xl, wkh, wkl, nullptr, p_kh, p_kl, kg, kbb, ps, nullptr, 1);
    gemm_mfma<<<ggrid, 256, 0, stream>>>(xh, xl, wvh, wvl, nullptr, p_vh, p_vl, nullptr, nullptr, 1.f, nullptr, 2);

    dim3 agrid(T_SEQ / 256, HEADS, B_SZ);
    attn_mfma<<<agrid, 512, 0, stream>>>(p_qh, p_ql, p_kh, p_kl, p_vh, p_vl, mask, xh, xl);

    gemm_mfma<<<ggrid, 256, 0, stream>>>(xh, xl, woh, wol, out, nullptr, nullptr, nullptr, nullptr, 1.f, bo, 0);
}

// Round 11
// 515.888 us; speedup vs baseline: 1.9378x; 1.1012x over previous
//
#include <hip/hip_runtime.h>
#include <math.h>

#define B_SZ   4
#define T_SEQ  2048
#define EMB    1024
#define HEADS  16
#define HS     64
#define M_TOT  (B_SZ * T_SEQ)   // 8192

typedef unsigned short u16;
using f32x4  = __attribute__((ext_vector_type(4))) float;
using bf16x8 = __attribute__((ext_vector_type(8))) short;
using u16x8  = __attribute__((ext_vector_type(8))) unsigned short;
using u16x4  = __attribute__((ext_vector_type(4))) unsigned short;

#define EXP2F(x) __builtin_amdgcn_exp2f(x)   // v_exp_f32 (base-2); __exp2f collides with glibc macro

// async global->LDS, 16B per lane; LDS dest is wave-uniform base, HW adds lane*16
__device__ __forceinline__ void async16(u16* lds, const u16* g) {
    __builtin_amdgcn_global_load_lds(
        (const __attribute__((address_space(1))) unsigned int*)g,
        (__attribute__((address_space(3))) unsigned int*)lds, 16, 0, 0);
}

__device__ __forceinline__ u16 bf16_rne(float f) {
    unsigned u = __float_as_uint(f);
    return (u16)((u + 0x7fffu + ((u >> 16) & 1u)) >> 16);
}
__device__ __forceinline__ void split2(float f, u16& h, u16& l) {
    h = bf16_rne(f);
    float hf = __uint_as_float(((unsigned)h) << 16);
    l = bf16_rne(f - hf);
}
__device__ __forceinline__ unsigned cvt_pk_bf16(float a, float b) {
    unsigned r;
    asm("v_cvt_pk_bf16_f32 %0, %1, %2" : "=v"(r) : "v"(a), "v"(b));
    return r;
}

// ---------------------------------------------------------------------------
// One merged split pass: x (8 regions) + Wq/Wk/Wv/Wo (1 region each).
// ---------------------------------------------------------------------------
__global__ __launch_bounds__(256) void split_all(
    const float* __restrict__ x,  const float* __restrict__ wq,
    const float* __restrict__ wk, const float* __restrict__ wv,
    const float* __restrict__ wo,
    u16* __restrict__ xh,  u16* __restrict__ xl,
    u16* __restrict__ wqh, u16* __restrict__ wql,
    u16* __restrict__ wkh, u16* __restrict__ wkl,
    u16* __restrict__ wvh, u16* __restrict__ wvl,
    u16* __restrict__ woh, u16* __restrict__ wol)
{
    int i = blockIdx.x * 256 + threadIdx.x;
    int r = i >> 18;
    const float* src; u16* dh; u16* dl; int off;
    if (r < 8)       { src = x;  dh = xh;  dl = xl;  off = i; }
    else if (r == 8) { src = wq; dh = wqh; dl = wql; off = i - (8 << 18); }
    else if (r == 9) { src = wk; dh = wkh; dl = wkl; off = i - (9 << 18); }
    else if (r == 10){ src = wv; dh = wvh; dl = wvl; off = i - (10 << 18); }
    else             { src = wo; dh = woh; dl = wol; off = i - (11 << 18); }
    float4 v = ((const float4*)src)[off];
    float f[4] = {v.x, v.y, v.z, v.w};
    u16 hh[4], ll[4];
    #pragma unroll
    for (int j = 0; j < 4; ++j) split2(f[j], hh[j], ll[j]);
    uint2 H, L;
    H.x = (unsigned)hh[0] | ((unsigned)hh[1] << 16);
    H.y = (unsigned)hh[2] | ((unsigned)hh[3] << 16);
    L.x = (unsigned)ll[0] | ((unsigned)ll[1] << 16);
    L.y = (unsigned)ll[2] | ((unsigned)ll[3] << 16);
    ((uint2*)dh)[off] = H;
    ((uint2*)dl)[off] = L;
}

// ---------------------------------------------------------------------------
// Split-bf16 MFMA GEMM (known-good, unchanged).
// mode 0: fp32 out + bias; mode 1: per-head LN -> hi/lo bf16;
// mode 2: hi/lo bf16 transposed Vt[b][h][d][t].
// ---------------------------------------------------------------------------
#define BM 128
#define BN 128
#define BKB 32

__global__ __launch_bounds__(256, 2) void gemm_mfma(
    const u16* __restrict__ Ah, const u16* __restrict__ Al,
    const u16* __restrict__ Wh, const u16* __restrict__ Wl,
    float* __restrict__ Cf, u16* __restrict__ Chi, u16* __restrict__ Clo,
    const float* __restrict__ lng, const float* __restrict__ lnb,
    float post_scale, const float* __restrict__ bias, int mode)
{
    __shared__ u16 sAh[BM * BKB], sAl[BM * BKB];
    __shared__ u16 sBh[BN * BKB], sBl[BN * BKB];
    const int tid = threadIdx.x;
    const int w = tid >> 6, lane = tid & 63;
    const int wr = w >> 1, wc = w & 1;
    const int m0 = blockIdx.x * BM, n0 = blockIdx.y * BN;
    const int fr = lane & 15, kc = (lane >> 4) * 8;
    const int srow = lane >> 2, schunk = (lane & 3) * 8;

    f32x4 acc[4][4] = {};

    for (int k0 = 0; k0 < EMB; k0 += BKB) {
        #pragma unroll
        for (int c = 0; c < 2; ++c) {
            int r = (w * 2 + c) * 16 + srow;
            size_t gA = (size_t)(m0 + r) * EMB + k0 + schunk;
            size_t gB = (size_t)(n0 + r) * EMB + k0 + schunk;
            int lb = (w * 2 + c) * 512;
            async16(&sAh[lb], Ah + gA);
            async16(&sAl[lb], Al + gA);
            async16(&sBh[lb], Wh + gB);
            async16(&sBl[lb], Wl + gB);
        }
        __syncthreads();

        bf16x8 bh[4], bl[4];
        #pragma unroll
        for (int ni = 0; ni < 4; ++ni) {
            int row = wc * 64 + ni * 16 + fr;
            bh[ni] = *(const bf16x8*)&sBh[row * BKB + kc];
            bl[ni] = *(const bf16x8*)&sBl[row * BKB + kc];
        }
        #pragma unroll
        for (int mi = 0; mi < 4; ++mi) {
            int row = wr * 64 + mi * 16 + fr;
            bf16x8 ah = *(const bf16x8*)&sAh[row * BKB + kc];
            bf16x8 al = *(const bf16x8*)&sAl[row * BKB + kc];
            #pragma unroll
            for (int ni = 0; ni < 4; ++ni) {
                acc[mi][ni] = __builtin_amdgcn_mfma_f32_16x16x32_bf16(ah, bh[ni], acc[mi][ni], 0, 0, 0);
                acc[mi][ni] = __builtin_amdgcn_mfma_f32_16x16x32_bf16(ah, bl[ni], acc[mi][ni], 0, 0, 0);
                acc[mi][ni] = __builtin_amdgcn_mfma_f32_16x16x32_bf16(al, bh[ni], acc[mi][ni], 0, 0, 0);
            }
        }
        __syncthreads();
    }

    if (mode == 1) {
        float g4[4], b4[4];
        #pragma unroll
        for (int ni = 0; ni < 4; ++ni) {
            int dd = ni * 16 + fr;
            g4[ni] = lng[dd];
            b4[ni] = lnb[dd];
        }
        #pragma unroll
        for (int mi = 0; mi < 4; ++mi) {
            #pragma unroll
            for (int i = 0; i < 4; ++i) {
                float s = acc[mi][0][i] + acc[mi][1][i] + acc[mi][2][i] + acc[mi][3][i];
                #pragma unroll
                for (int off = 1; off < 16; off <<= 1) s += __shfl_xor(s, off);
                float mu = s * (1.f / HS);
                float d2 = 0.f;
                #pragma unroll
                for (int ni = 0; ni < 4; ++ni) {
                    float d = acc[mi][ni][i] - mu;
                    d2 += d * d;
                }
                #pragma unroll
                for (int off = 1; off < 16; off <<= 1) d2 += __shfl_xor(d2, off);
                float rs = rsqrtf(d2 * (1.f / HS) + 1e-5f);
                #pragma unroll
                for (int ni = 0; ni < 4; ++ni)
                    acc[mi][ni][i] = ((acc[mi][ni][i] - mu) * rs * g4[ni] + b4[ni]) * post_scale;
            }
        }
    }

    #pragma unroll
    for (int mi = 0; mi < 4; ++mi) {
        #pragma unroll
        for (int ni = 0; ni < 4; ++ni) {
            const int col = n0 + wc * 64 + ni * 16 + fr;
            const int rowb = m0 + wr * 64 + mi * 16 + (lane >> 4) * 4;
            if (mode == 0) {
                float badd = bias[col];
                #pragma unroll
                for (int i = 0; i < 4; ++i)
                    Cf[(size_t)(rowb + i) * EMB + col] = acc[mi][ni][i] + badd;
            } else if (mode == 1) {
                #pragma unroll
                for (int i = 0; i < 4; ++i) {
                    u16 hh, ll; split2(acc[mi][ni][i], hh, ll);
                    Chi[(size_t)(rowb + i) * EMB + col] = hh;
                    Clo[(size_t)(rowb + i) * EMB + col] = ll;
                }
            } else {
                int hh = col >> 6, d = col & 63;
                int bb = rowb >> 11, t0 = rowb & 2047;
                u16x4 H, L;
                #pragma unroll
                for (int i = 0; i < 4; ++i) {
                    u16 vh, vl; split2(acc[mi][ni][i], vh, vl);
                    H[i] = vh; L[i] = vl;
                }
                size_t off = ((size_t)((bb * HEADS + hh) * HS + d)) * T_SEQ + t0;
                *(u16x4*)(Chi + off) = H;
                *(u16x4*)(Clo + off) = L;
            }
        }
    }
}

// ---------------------------------------------------------------------------
// MFMA flash attention v3.2: v3.1 structure (8 waves x 32 q, 512 thr, 2 blk/CU)
//  + T2 XOR chunk-swizzle on all LDS tiles (stride 64 u16, chunk ^= row&7):
//    kills the 8-way bank conflict of the padded-72 layout (r8: 2.3e7 conflicts)
//  + T14 async-stage: next tile's K/V half + mask prefetched to regs after
//    barrier(1), ds_written at next loop top (HBM latency hides under compute)
//  + T13 defer-max + log2-domain softmax (Q pre-scaled by log2e; exp2)
// ---------------------------------------------------------------------------
__global__ __launch_bounds__(512, 2) void attn_mfma(
    const u16* __restrict__ qh, const u16* __restrict__ ql,
    const u16* __restrict__ kh, const u16* __restrict__ kl,
    const u16* __restrict__ vh, const u16* __restrict__ vl,
    const int* __restrict__ mask,
    u16* __restrict__ oh, u16* __restrict__ ol)
{
    __shared__ u16 sKh[64 * 64], sKl[64 * 64], sVh[64 * 64], sVl[64 * 64];
    __shared__ u16 sPs[8][32 * 64];
    __shared__ float kmsh[64];
    __shared__ float qmsh[256];
    __shared__ float fb[8][32];

    const int tid = threadIdx.x;
    const int w = tid >> 6, lane = tid & 63;
    const int fr = lane & 15, g = lane >> 4;
    const int xr = fr & 7;                    // read-side swizzle key (== row&7)
    const int q0 = blockIdx.x * 256;
    const int h = blockIdx.y, b = blockIdx.z;

    if (tid < 256) qmsh[tid] = (float)mask[b * T_SEQ + q0 + tid];

    // staging: wave w -> buffer (w>>1), half (w&1); 32 rows x 64 u16 per wave
    const int bsel = w >> 1, half = w & 1;
    const u16* gsrc; u16* sdst; int rstr; size_t kstep;
    if (bsel == 0)      { gsrc = kh + (size_t)b * T_SEQ * EMB + h * HS; sdst = sKh; rstr = EMB;   kstep = (size_t)64 * EMB; }
    else if (bsel == 1) { gsrc = kl + (size_t)b * T_SEQ * EMB + h * HS; sdst = sKl; rstr = EMB;   kstep = (size_t)64 * EMB; }
    else if (bsel == 2) { gsrc = vh + (size_t)(b * HEADS + h) * HS * T_SEQ; sdst = sVh; rstr = T_SEQ; kstep = 64; }
    else                { gsrc = vl + (size_t)(b * HEADS + h) * HS * T_SEQ; sdst = sVl; rstr = T_SEQ; kstep = 64; }
    gsrc += (size_t)half * 32 * rstr;
    sdst += half * 32 * 64;
    // per-lane source / swizzled LDS dest (row&7 == wrow since rows step by 8)
    const int wrow = lane >> 3;                       // local row 0..7 per 8-row group
    const int wchunk = (lane & 7) ^ wrow;             // XOR swizzle on write
    const u16* lsrc = gsrc + (size_t)wrow * rstr + (lane & 7) * 8;
    u16* ldst = sdst + wrow * 64 + (wchunk << 3);

    // Q fragments in registers (B-operand of swapped QK^T); wave owns 32 q-rows
    bf16x8 qfh[2][2], qfl[2][2];
    #pragma unroll
    for (int nf = 0; nf < 2; ++nf)
        #pragma unroll
        for (int ks = 0; ks < 2; ++ks) {
            size_t off = (size_t)(b * T_SEQ + q0 + w * 32 + nf * 16 + fr) * EMB
                         + h * HS + g * 8 + ks * 32;
            qfh[nf][ks] = *(const bf16x8*)(qh + off);
            qfl[nf][ks] = *(const bf16x8*)(ql + off);
        }

    f32x4 o[2][4] = {};
    float mrun[2] = {-INFINITY, -INFINITY}, lrun[2] = {0.f, 0.f};
    u16* Psw = sPs[w];

    // prologue: prefetch tile 0 into registers (T14)
    u16x8 stg[4];
    #pragma unroll
    for (int it = 0; it < 4; ++it)
        stg[it] = *(const u16x8*)(lsrc + (size_t)it * 8 * rstr);
    int kmreg = mask[b * T_SEQ + (tid & 63)];

    const int NT = T_SEQ / 64;
    for (int kt = 0; kt < NT; ++kt) {
        // ---- commit prefetched tile to LDS (swizzled) ----
        #pragma unroll
        for (int it = 0; it < 4; ++it)
            *(u16x8*)(ldst + it * 8 * 64) = stg[it];
        if (tid < 64) kmsh[tid] = (float)kmreg;
        __syncthreads();

        // ---- issue next tile's loads (latency hides under compute) ----
        if (kt + 1 < NT) {
            const u16* s = lsrc + (size_t)(kt + 1) * kstep;
            #pragma unroll
            for (int it = 0; it < 4; ++it)
                stg[it] = *(const u16x8*)(s + (size_t)it * 8 * rstr);
            kmreg = mask[b * T_SEQ + (kt + 1) * 64 + (tid & 63)];
        }

        float kmv[4][4]; int anyv = 0;
        #pragma unroll
        for (int mf = 0; mf < 4; ++mf)
            #pragma unroll
            for (int i = 0; i < 4; ++i) {
                kmv[mf][i] = kmsh[mf * 16 + g * 4 + i];
                anyv |= (kmv[mf][i] != 0.f);
            }

        if (__any(anyv)) {
            // ---- QK^T (swapped): st[key][q], swizzled K reads ----
            f32x4 st[4][2] = {};
            #pragma unroll
            for (int ks = 0; ks < 2; ++ks) {
                bf16x8 ka[4], kb[4];
                #pragma unroll
                for (int mf = 0; mf < 4; ++mf) {
                    int ridx = ((mf * 16 + fr) << 6) + (((g + 4 * ks) ^ xr) << 3);
                    ka[mf] = *(const bf16x8*)&sKh[ridx];
                    kb[mf] = *(const bf16x8*)&sKl[ridx];
                }
                __builtin_amdgcn_s_setprio(1);
                #pragma unroll
                for (int mf = 0; mf < 4; ++mf)
                    #pragma unroll
                    for (int nf = 0; nf < 2; ++nf) {
                        st[mf][nf] = __builtin_amdgcn_mfma_f32_16x16x32_bf16(ka[mf], qfh[nf][ks], st[mf][nf], 0, 0, 0);
                        st[mf][nf] = __builtin_amdgcn_mfma_f32_16x16x32_bf16(ka[mf], qfl[nf][ks], st[mf][nf], 0, 0, 0);
                        st[mf][nf] = __builtin_amdgcn_mfma_f32_16x16x32_bf16(kb[mf], qfh[nf][ks], st[mf][nf], 0, 0, 0);
                    }
                __builtin_amdgcn_s_setprio(0);
            }
            // ---- online softmax, log2 domain, defer-max (per q = fr + 16*nf) ----
            #pragma unroll
            for (int nf = 0; nf < 2; ++nf) {
                float tm = -INFINITY;
                #pragma unroll
                for (int mf = 0; mf < 4; ++mf)
                    #pragma unroll
                    for (int i = 0; i < 4; ++i) {
                        float s = (kmv[mf][i] != 0.f) ? st[mf][nf][i] : -INFINITY;
                        st[mf][nf][i] = s;
                        tm = fmaxf(tm, s);
                    }
                tm = fmaxf(tm, __shfl_xor(tm, 16));
                tm = fmaxf(tm, __shfl_xor(tm, 32));
                // defer: keep old max while growth <= 8 (log2 units, P <= 256)
                if (!__all(tm <= mrun[nf] + 8.0f)) {
                    float mn = fmaxf(mrun[nf], tm);
                    float f = EXP2F(mrun[nf] - mn);   // -inf -> 0 on first tile
                    fb[w][nf * 16 + fr] = f;
                    lrun[nf] *= f;
                    mrun[nf] = mn;
                    float f0 = fb[w][nf * 16 + g * 4 + 0];
                    float f1 = fb[w][nf * 16 + g * 4 + 1];
                    float f2 = fb[w][nf * 16 + g * 4 + 2];
                    float f3 = fb[w][nf * 16 + g * 4 + 3];
                    #pragma unroll
                    for (int nj = 0; nj < 4; ++nj) {
                        o[nf][nj][0] *= f0; o[nf][nj][1] *= f1;
                        o[nf][nj][2] *= f2; o[nf][nj][3] *= f3;
                    }
                }
                // P compute + pack to LDS (swizzled); guard the all -inf case
                if (mrun[nf] > -1e37f) {
                    float ps_ = 0.f;
                    #pragma unroll
                    for (int mf = 0; mf < 4; ++mf) {
                        float p0 = EXP2F(st[mf][nf][0] - mrun[nf]);
                        float p1 = EXP2F(st[mf][nf][1] - mrun[nf]);
                        float p2 = EXP2F(st[mf][nf][2] - mrun[nf]);
                        float p3 = EXP2F(st[mf][nf][3] - mrun[nf]);
                        ps_ += (p0 + p1) + (p2 + p3);
                        int idx = ((nf * 16 + fr) << 6)
                                + (((2 * mf + (g >> 1)) ^ xr) << 3) + (g & 1) * 4;
                        *(unsigned*)&Psw[idx]     = cvt_pk_bf16(p0, p1);
                        *(unsigned*)&Psw[idx + 2] = cvt_pk_bf16(p2, p3);
                    }
                    ps_ += __shfl_xor(ps_, 16);
                    ps_ += __shfl_xor(ps_, 32);
                    lrun[nf] += ps_;
                } else {
                    #pragma unroll
                    for (int mf = 0; mf < 4; ++mf) {
                        int idx = ((nf * 16 + fr) << 6)
                                + (((2 * mf + (g >> 1)) ^ xr) << 3) + (g & 1) * 4;
                        *(unsigned*)&Psw[idx]     = 0u;
                        *(unsigned*)&Psw[idx + 2] = 0u;
                    }
                }
            }
            // ---- PV (swizzled P/V reads) ----
            #pragma unroll
            for (int ks = 0; ks < 2; ++ks) {
                bf16x8 pa[2];
                #pragma unroll
                for (int mi = 0; mi < 2; ++mi)
                    pa[mi] = *(const bf16x8*)&Psw[((mi * 16 + fr) << 6) + (((g + 4 * ks) ^ xr) << 3)];
                __builtin_amdgcn_s_setprio(1);
                #pragma unroll
                for (int nj = 0; nj < 4; ++nj) {
                    int ridx = ((nj * 16 + fr) << 6) + (((g + 4 * ks) ^ xr) << 3);
                    bf16x8 va = *(const bf16x8*)&sVh[ridx];
                    bf16x8 vb = *(const bf16x8*)&sVl[ridx];
                    #pragma unroll
                    for (int mi = 0; mi < 2; ++mi) {
                        o[mi][nj] = __builtin_amdgcn_mfma_f32_16x16x32_bf16(pa[mi], va, o[mi][nj], 0, 0, 0);
                        o[mi][nj] = __builtin_amdgcn_mfma_f32_16x16x32_bf16(pa[mi], vb, o[mi][nj], 0, 0, 0);
                    }
                }
                __builtin_amdgcn_s_setprio(0);
            }
        }
        __syncthreads();
    }

    // ---- epilogue: normalize, mask q, write hi/lo bf16 ----
    #pragma unroll
    for (int nf = 0; nf < 2; ++nf) fb[w][nf * 16 + fr] = lrun[nf];
    #pragma unroll
    for (int mi = 0; mi < 2; ++mi) {
        #pragma unroll
        for (int i = 0; i < 4; ++i) {
            float lq = fb[w][mi * 16 + g * 4 + i];
            float qv = qmsh[w * 32 + mi * 16 + g * 4 + i];
            float inv = (qv != 0.f && lq > 0.f) ? 1.f / lq : 0.f;
            size_t row = (size_t)(b * T_SEQ + q0 + w * 32 + mi * 16 + g * 4 + i);
            #pragma unroll
            for (int nj = 0; nj < 4; ++nj) {
                float v = o[mi][nj][i] * inv;
                u16 hh, ll; split2(v, hh, ll);
                size_t off = row * EMB + h * HS + nj * 16 + fr;
                oh[off] = hh;
                ol[off] = ll;
            }
        }
    }
}

// ---------------------------------------------------------------------------
extern "C" void kernel_launch(void* const* d_in, const int* in_sizes, int n_in,
                              void* d_out, int out_size, void* d_ws, size_t ws_size,
                              hipStream_t stream)
{
    const float* x    = (const float*)d_in[0];
    const int*   mask = (const int*)d_in[1];
    const float* Wk   = (const float*)d_in[2];
    const float* Wq   = (const float*)d_in[3];
    const float* Wv   = (const float*)d_in[4];
    const float* Wo   = (const float*)d_in[5];
    const float* bo   = (const float*)d_in[6];
    const float* kg   = (const float*)d_in[7];
    const float* kbb  = (const float*)d_in[8];
    const float* qg   = (const float*)d_in[9];
    const float* qbb  = (const float*)d_in[10];
    float* out = (float*)d_out;

    const size_t NELT = (size_t)M_TOT * EMB;   // 8,388,608
    const size_t WELT = (size_t)EMB * EMB;     // 1,048,576
    u16* xh  = (u16*)d_ws;            // also reused as attn output hi
    u16* xl  = xh + NELT;             // also reused as attn output lo
    u16* p_qh = xl + NELT;
    u16* p_ql = p_qh + NELT;
    u16* p_kh = p_ql + NELT;
    u16* p_kl = p_kh + NELT;
    u16* p_vh = p_kl + NELT;          // transposed [b][h][d][t]
    u16* p_vl = p_vh + NELT;
    u16* wqh = p_vl + NELT;
    u16* wql = wqh + WELT;
    u16* wkh = wql + WELT;
    u16* wkl = wkh + WELT;
    u16* wvh = wkl + WELT;
    u16* wvl = wvh + WELT;
    u16* woh = wvl + WELT;
    u16* wol = woh + WELT;

    const float ps   = 0.17677669529663687f;                      // 1024^(-1/4)
    const float ps_q = 0.17677669529663687f * 1.44269504088896f;  // * log2(e): attn uses exp2

    split_all<<<12288, 256, 0, stream>>>(x, Wq, Wk, Wv, Wo,
        xh, xl, wqh, wql, wkh, wkl, wvh, wvl, woh, wol);

    dim3 ggrid(M_TOT / BM, EMB / BN);
    gemm_mfma<<<ggrid, 256, 0, stream>>>(xh, xl, wqh, wql, nullptr, p_qh, p_ql, qg, qbb, ps_q, nullptr, 1);
    gemm_mfma<<<ggrid, 256, 0, stream>>>(xh, xl, wkh, wkl, nullptr, p_kh, p_kl, kg, kbb, ps, nullptr, 1);
    gemm_mfma<<<ggrid, 256, 0, stream>>>(xh, xl, wvh, wvl, nullptr, p_vh, p_vl, nullptr, nullptr, 1.f, nullptr, 2);

    dim3 agrid(T_SEQ / 256, HEADS, B_SZ);
    attn_mfma<<<agrid, 512, 0, stream>>>(p_qh, p_ql, p_kh, p_kl, p_vh, p_vl, mask, xh, xl);

    gemm_mfma<<<ggrid, 256, 0, stream>>>(xh, xl, woh, wol, out, nullptr, nullptr, nullptr, nullptr, 1.f, bo, 0);
}